// Round 14
// baseline (330.864 us; speedup 1.0000x reference)
//
#include <hip/hip_runtime.h>
#include <math.h>

#define N_NODES 100000
#define LN_EPS 1e-5f
#define NBUCK ((N_NODES + 255) / 256)  // 391 buckets of 256 nodes
#define EPB 8192                        // edges per block in place_reserve

typedef __attribute__((ext_vector_type(8))) short bf16x8;
typedef __attribute__((ext_vector_type(4))) float f32x4;

__device__ __forceinline__ unsigned short f2bf(float f) {
    unsigned int u = __float_as_uint(f);
    return (unsigned short)((u + 0x7FFFu + ((u >> 16) & 1u)) >> 16);
}
__device__ __forceinline__ float bf2f(unsigned short u) {
    return __uint_as_float(((unsigned int)u) << 16);
}

// 64-lane sum via DPP (levels 1-8 on VALU pipe) + xor16 swizzle + shfl32.
__device__ __forceinline__ float wsum64(float x) {
    x += __int_as_float(__builtin_amdgcn_update_dpp(0, __float_as_int(x), 0xB1, 0xF, 0xF, true));
    x += __int_as_float(__builtin_amdgcn_update_dpp(0, __float_as_int(x), 0x4E, 0xF, 0xF, true));
    x += __int_as_float(__builtin_amdgcn_update_dpp(0, __float_as_int(x), 0x141, 0xF, 0xF, true));
    x += __int_as_float(__builtin_amdgcn_update_dpp(0, __float_as_int(x), 0x140, 0xF, 0xF, true));
    x += __int_as_float(__builtin_amdgcn_ds_swizzle(__float_as_int(x), 0x401F));
    x += __shfl_xor(x, 32, 64);
    return x;
}

// ---- R14: weights converted ONCE to transposed bf16 (W^T[out][k], rows 16B-
// aligned). R13 counters showed gemm23 at 54us with MfmaUtil 2% — 95% of the
// time was per-block weight staging (25.6M f2bf + 8-way-conflict LDS stores,
// SQ_LDS_BANK_CONFLICT 3.3M, occupancy 25% from 53KB LDS). Weights are 55KB
// total and L2-resident: read MFMA B-fragments straight from global.
__global__ void prep_weights(const float* __restrict__ W1, const float* __restrict__ W2,
                             const float* __restrict__ W3, const float* __restrict__ L1,
                             const float* __restrict__ L2,
                             unsigned short* __restrict__ w1t, unsigned short* __restrict__ w2t,
                             unsigned short* __restrict__ w3t, unsigned short* __restrict__ l1t,
                             unsigned short* __restrict__ l2t) {
    int i = blockIdx.x * 256 + threadIdx.x;
    if (i < 8192) {                    // W1 [128][64] -> w1t [64][128]
        int k = i >> 6, o = i & 63;
        w1t[o * 128 + k] = f2bf(W1[i]);
    } else if (i < 16384) {            // W2 [64][128] -> w2t [128][64]
        int j = i - 8192, k = j >> 7, o = j & 127;
        w2t[o * 64 + k] = f2bf(W2[j]);
    } else if (i < 24576) {            // W3 [128][64] -> w3t [64][128]
        int j = i - 16384, k = j >> 6, o = j & 63;
        w3t[o * 128 + k] = f2bf(W3[j]);
    } else if (i < 26624) {            // lw1 [64][32] -> l1t [32][64]
        int j = i - 24576, k = j >> 5, o = j & 31;
        l1t[o * 64 + k] = f2bf(L1[j]);
    } else if (i < 27648) {            // lw2 [32][32] -> l2t [32][32]
        int j = i - 26624, k = j >> 5, o = j & 31;
        l2t[o * 32 + k] = f2bf(L2[j]);
    }
}

// ======== CSR build v3 (R13): fixed-cap slab reservation, 3 kernels ========
__global__ void place_reserve(const int* __restrict__ src, const int* __restrict__ dst,
                              int* __restrict__ tails, unsigned* __restrict__ bucket,
                              int cap, int E) {
    __shared__ int hist[NBUCK];
    __shared__ int lcur[NBUCK];
    for (int b = threadIdx.x; b < NBUCK; b += 512) hist[b] = 0;
    __syncthreads();
    int e0 = blockIdx.x * EPB;
#pragma unroll
    for (int i = 0; i < EPB / 512; ++i) {
        int e = e0 + i * 512 + (int)threadIdx.x;
        if (e < E) atomicAdd(&hist[((unsigned)dst[e]) >> 8], 1);
    }
    __syncthreads();
    for (int b = threadIdx.x; b < NBUCK; b += 512) {
        int c = hist[b];
        lcur[b] = (c > 0) ? (b * cap + atomicAdd(&tails[b], c)) : 0;
    }
    __syncthreads();
#pragma unroll
    for (int i = 0; i < EPB / 512; ++i) {
        int e = e0 + i * 512 + (int)threadIdx.x;
        if (e < E) {
            unsigned d = (unsigned)dst[e];
            unsigned s = (unsigned)src[e];
            int p = atomicAdd(&lcur[d >> 8], 1);
            bucket[p] = ((d & 255u) << 24) | s;
        }
    }
}

__global__ void scan_base(const int* __restrict__ tails, int* __restrict__ base, int E) {
    __shared__ int s[512];
    int i = threadIdx.x;
    int v = (i < NBUCK) ? tails[i] : 0;
    s[i] = v;
    __syncthreads();
    for (int off = 1; off < 512; off <<= 1) {
        int t = (i >= off) ? s[i - off] : 0;
        __syncthreads();
        s[i] += t;
        __syncthreads();
    }
    if (i < NBUCK) base[i] = s[i] - v;
    if (i == 0) base[NBUCK] = E;
}

__global__ void build_csr_node(const unsigned* __restrict__ bucket, const int* __restrict__ tails,
                               const int* __restrict__ base, int* __restrict__ offsets,
                               float* __restrict__ dinv, int* __restrict__ csr,
                               int cap, int E) {
    __shared__ int hist[256];
    __shared__ int cur[256];
    int b = blockIdx.x, t = threadIdx.x;
    int r0 = b << 8;
    hist[t] = 0;
    __syncthreads();
    int s0 = b * cap, s1 = s0 + tails[b];
    for (int e = s0 + t; e < s1; e += 256)
        atomicAdd(&hist[bucket[e] >> 24], 1);
    __syncthreads();
    int deg = hist[t];
    for (int off = 1; off < 256; off <<= 1) {
        int tv = (t >= off) ? hist[t - off] : 0;
        __syncthreads();
        hist[t] += tv;
        __syncthreads();
    }
    int excl = hist[t] - deg;
    int node = r0 + t;
    int cbase = base[b];
    if (node < N_NODES) {
        offsets[node] = cbase + excl;
        dinv[node] = rsqrtf((float)deg + 1.f);
        cur[t] = cbase + excl;
    }
    if (node == N_NODES - 1) offsets[N_NODES] = E;
    __syncthreads();
    for (int e = s0 + t; e < s1; e += 256) {
        unsigned u = bucket[e];
        int p = atomicAdd(&cur[u >> 24], 1);
        csr[p] = (int)(u & 0xFFFFFFu);
    }
}

// ---------------- MFMA gemm: Y = X[n,K] @ W (+bias/LN/ELU/dinv); weights from global bf16 W^T ----
template <int K, int OUT, bool LN, bool BIAS, bool AF32, bool OF32, bool SCALED>
__launch_bounds__(256)
__global__ void mfma_gemm(const void* __restrict__ Xv, const unsigned short* __restrict__ WT,
                          const float* __restrict__ bias, const float* __restrict__ gamma,
                          const float* __restrict__ beta, void* __restrict__ Yv, int n,
                          const float* __restrict__ dinvp) {
    constexpr int T = OUT / 16;

    int wv = threadIdx.x >> 6, lane = threadIdx.x & 63;
    int quad = lane >> 4, l16 = lane & 15;
    int m0 = (blockIdx.x * 4 + wv) * 16;
    int rowc = min(m0 + l16, n - 1);

    f32x4 acc[T];
#pragma unroll
    for (int t = 0; t < T; ++t) acc[t] = (f32x4){0.f, 0.f, 0.f, 0.f};

#pragma unroll
    for (int s = 0; s < K / 32; ++s) {
        int koff = s * 32 + quad * 8;
        bf16x8 af;
        if (AF32) {
            const float4* X4 = (const float4*)Xv;
            size_t base = ((size_t)rowc * K + koff) >> 2;
            float4 a0 = X4[base];
            float4 a1 = X4[base + 1];
            af[0] = (short)f2bf(a0.x); af[1] = (short)f2bf(a0.y);
            af[2] = (short)f2bf(a0.z); af[3] = (short)f2bf(a0.w);
            af[4] = (short)f2bf(a1.x); af[5] = (short)f2bf(a1.y);
            af[6] = (short)f2bf(a1.z); af[7] = (short)f2bf(a1.w);
        } else {
            const unsigned short* Xb = (const unsigned short*)Xv;
            af = *(const bf16x8*)(Xb + (size_t)rowc * K + koff);
        }
#pragma unroll
        for (int t = 0; t < T; ++t) {
            const bf16x8 bfrag = *(const bf16x8*)(WT + (size_t)(t * 16 + l16) * K + koff);
            acc[t] = __builtin_amdgcn_mfma_f32_16x16x32_bf16(af, bfrag, acc[t], 0, 0, 0);
        }
    }

    float bj[T], gj[T], btj[T];
#pragma unroll
    for (int t = 0; t < T; ++t) {
        int c = t * 16 + l16;
        bj[t]  = BIAS ? bias[c] : 0.f;
        gj[t]  = LN ? gamma[c] : 1.f;
        btj[t] = LN ? beta[c] : 0.f;
    }

    float* Yf = (float*)Yv;
    unsigned short* Yb = (unsigned short*)Yv;

    if (LN) {
        float s[4] = {0.f, 0.f, 0.f, 0.f}, sq[4] = {0.f, 0.f, 0.f, 0.f};
#pragma unroll
        for (int t = 0; t < T; ++t)
#pragma unroll
            for (int r = 0; r < 4; ++r) {
                float v = acc[t][r] + bj[t];
                s[r] += v;
                sq[r] += v * v;
            }
#pragma unroll
        for (int off = 1; off < 16; off <<= 1)
#pragma unroll
            for (int r = 0; r < 4; ++r) {
                s[r] += __shfl_xor(s[r], off, 64);
                sq[r] += __shfl_xor(sq[r], off, 64);
            }
        float mu[4], rs[4];
#pragma unroll
        for (int r = 0; r < 4; ++r) {
            mu[r] = s[r] / OUT;
            float var = sq[r] / OUT - mu[r] * mu[r];
            rs[r] = rsqrtf(var + LN_EPS);
        }
#pragma unroll
        for (int r = 0; r < 4; ++r) {
            int rowg = m0 + quad * 4 + r;
            if (rowg < n) {
                float dv = SCALED ? dinvp[rowg] : 1.f;
#pragma unroll
                for (int t = 0; t < T; ++t) {
                    float y = (acc[t][r] + bj[t] - mu[r]) * rs[r] * gj[t] + btj[t];
                    y = y > 0.f ? y : expm1f(y);
                    if (SCALED) y *= dv;
                    size_t idx = (size_t)rowg * OUT + t * 16 + l16;
                    if (OF32) Yf[idx] = y; else Yb[idx] = f2bf(y);
                }
            }
        }
    } else {
#pragma unroll
        for (int r = 0; r < 4; ++r) {
            int rowg = m0 + quad * 4 + r;
            if (rowg < n) {
                float dv = SCALED ? dinvp[rowg] : 1.f;
#pragma unroll
                for (int t = 0; t < T; ++t) {
                    float y = acc[t][r] + bj[t];
                    if (SCALED) y *= dv;
                    size_t idx = (size_t)rowg * OUT + t * 16 + l16;
                    if (OF32) Yf[idx] = y; else Yb[idx] = f2bf(y);
                }
            }
        }
    }
}

// ---------------- fused gemm2+gemm3: xs2 = dinv * (LN_ELU(a2@W2+b2) @ W3) ----------------
// Weights from global bf16 (w2t [128][64], w3t [64][128]); only the sT
// transpose tile remains in LDS (17.4KB -> ~7 blocks/CU vs R13's 3).
// In-place X==Y safe: each wave reads only its own 16 rows before writing.
__launch_bounds__(256)
__global__ void gemm23_fused(const unsigned short* __restrict__ X,
                             const unsigned short* __restrict__ w2t, const float* __restrict__ b2f,
                             const float* __restrict__ g2, const float* __restrict__ be2,
                             const unsigned short* __restrict__ w3t, const float* __restrict__ dinvp,
                             unsigned short* __restrict__ Y, int n) {
    constexpr int TS = 136;
    __shared__ __align__(16) unsigned short sT[4][16 * TS];   // 17.4KB

    int wv = threadIdx.x >> 6, lane = threadIdx.x & 63;
    int quad = lane >> 4, l16 = lane & 15;
    int m0 = (blockIdx.x * 4 + wv) * 16;
    int rowc = min(m0 + l16, n - 1);

    // MFMA1: [16x64] @ W2 -> [16x128]
    f32x4 acc[8];
#pragma unroll
    for (int t = 0; t < 8; ++t) acc[t] = (f32x4){0.f, 0.f, 0.f, 0.f};
#pragma unroll
    for (int s = 0; s < 2; ++s) {
        int koff = s * 32 + quad * 8;
        bf16x8 af = *(const bf16x8*)(X + (size_t)rowc * 64 + koff);
#pragma unroll
        for (int t = 0; t < 8; ++t) {
            const bf16x8 bfrag = *(const bf16x8*)(w2t + (size_t)(t * 16 + l16) * 64 + koff);
            acc[t] = __builtin_amdgcn_mfma_f32_16x16x32_bf16(af, bfrag, acc[t], 0, 0, 0);
        }
    }

    // bias + LN(128) + ELU -> transpose tile
    float bj[8], gj[8], btj[8];
#pragma unroll
    for (int t = 0; t < 8; ++t) {
        int c = t * 16 + l16;
        bj[t] = b2f[c]; gj[t] = g2[c]; btj[t] = be2[c];
    }
    float s4[4] = {0.f, 0.f, 0.f, 0.f}, sq4[4] = {0.f, 0.f, 0.f, 0.f};
#pragma unroll
    for (int t = 0; t < 8; ++t)
#pragma unroll
        for (int r = 0; r < 4; ++r) {
            float v = acc[t][r] + bj[t];
            s4[r] += v;
            sq4[r] += v * v;
        }
#pragma unroll
    for (int off = 1; off < 16; off <<= 1)
#pragma unroll
        for (int r = 0; r < 4; ++r) {
            s4[r] += __shfl_xor(s4[r], off, 64);
            sq4[r] += __shfl_xor(sq4[r], off, 64);
        }
#pragma unroll
    for (int r = 0; r < 4; ++r) {
        float mu = s4[r] * (1.f / 128.f);
        float var = sq4[r] * (1.f / 128.f) - mu * mu;
        float rs = rsqrtf(var + LN_EPS);
#pragma unroll
        for (int t = 0; t < 8; ++t) {
            float z = (acc[t][r] + bj[t] - mu) * rs * gj[t] + btj[t];
            z = z > 0.f ? z : expm1f(z);
            sT[wv][(quad * 4 + r) * TS + t * 16 + l16] = f2bf(z);
        }
    }
    __syncthreads();

    // MFMA2: [16x128] @ W3 -> [16x64], scale by dinv
    f32x4 acc2[4];
#pragma unroll
    for (int t = 0; t < 4; ++t) acc2[t] = (f32x4){0.f, 0.f, 0.f, 0.f};
#pragma unroll
    for (int s = 0; s < 4; ++s) {
        int koff = s * 32 + quad * 8;
        bf16x8 af = *(const bf16x8*)&sT[wv][l16 * TS + koff];
#pragma unroll
        for (int t = 0; t < 4; ++t) {
            const bf16x8 bfrag = *(const bf16x8*)(w3t + (size_t)(t * 16 + l16) * 128 + koff);
            acc2[t] = __builtin_amdgcn_mfma_f32_16x16x32_bf16(af, bfrag, acc2[t], 0, 0, 0);
        }
    }
#pragma unroll
    for (int r = 0; r < 4; ++r) {
        int rowg = m0 + quad * 4 + r;
        if (rowg < n) {
            float dv = dinvp[rowg];
#pragma unroll
            for (int t = 0; t < 4; ++t)
                Y[(size_t)rowg * 64 + t * 16 + l16] = f2bf(acc2[t][r] * dv);
        }
    }
}

// ---------------- fused lin1+lin2: out = LN_ELU(X@lw1+lb1) @ lw2 + lb2 ----------------
__launch_bounds__(256)
__global__ void lin_fused(const unsigned short* __restrict__ X, const unsigned short* __restrict__ l1t,
                          const float* __restrict__ b1f, const float* __restrict__ g,
                          const float* __restrict__ be, const unsigned short* __restrict__ l2t,
                          const float* __restrict__ b2f, float* __restrict__ out, int n) {
    constexpr int TS = 56;
    __shared__ __align__(16) unsigned short sT[4][16 * TS];

    int wv = threadIdx.x >> 6, lane = threadIdx.x & 63;
    int quad = lane >> 4, l16 = lane & 15;
    int m0 = (blockIdx.x * 4 + wv) * 16;
    int rowc = min(m0 + l16, n - 1);

    f32x4 acc[2];
    acc[0] = (f32x4){0.f, 0.f, 0.f, 0.f};
    acc[1] = (f32x4){0.f, 0.f, 0.f, 0.f};
#pragma unroll
    for (int s = 0; s < 2; ++s) {
        int koff = s * 32 + quad * 8;
        bf16x8 af = *(const bf16x8*)(X + (size_t)rowc * 64 + koff);
#pragma unroll
        for (int t = 0; t < 2; ++t) {
            const bf16x8 bfrag = *(const bf16x8*)(l1t + (size_t)(t * 16 + l16) * 64 + koff);
            acc[t] = __builtin_amdgcn_mfma_f32_16x16x32_bf16(af, bfrag, acc[t], 0, 0, 0);
        }
    }

    float bj[2], gj[2], btj[2];
#pragma unroll
    for (int t = 0; t < 2; ++t) {
        int c = t * 16 + l16;
        bj[t] = b1f[c]; gj[t] = g[c]; btj[t] = be[c];
    }
    float s4[4] = {0.f, 0.f, 0.f, 0.f}, sq4[4] = {0.f, 0.f, 0.f, 0.f};
#pragma unroll
    for (int t = 0; t < 2; ++t)
#pragma unroll
        for (int r = 0; r < 4; ++r) {
            float v = acc[t][r] + bj[t];
            s4[r] += v;
            sq4[r] += v * v;
        }
#pragma unroll
    for (int off = 1; off < 16; off <<= 1)
#pragma unroll
        for (int r = 0; r < 4; ++r) {
            s4[r] += __shfl_xor(s4[r], off, 64);
            sq4[r] += __shfl_xor(sq4[r], off, 64);
        }
#pragma unroll
    for (int r = 0; r < 4; ++r) {
        float mu = s4[r] * (1.f / 32.f);
        float var = sq4[r] * (1.f / 32.f) - mu * mu;
        float rs = rsqrtf(var + LN_EPS);
#pragma unroll
        for (int t = 0; t < 2; ++t) {
            float z = (acc[t][r] + bj[t] - mu) * rs * gj[t] + btj[t];
            z = z > 0.f ? z : expm1f(z);
            sT[wv][(quad * 4 + r) * TS + t * 16 + l16] = f2bf(z);
        }
    }
    __syncthreads();

    bf16x8 a2 = *(const bf16x8*)&sT[wv][l16 * TS + quad * 8];
    f32x4 acc2[2];
#pragma unroll
    for (int t = 0; t < 2; ++t) {
        const bf16x8 bfrag = *(const bf16x8*)(l2t + (size_t)(t * 16 + l16) * 32 + quad * 8);
        acc2[t] = __builtin_amdgcn_mfma_f32_16x16x32_bf16(
            a2, bfrag, (f32x4){0.f, 0.f, 0.f, 0.f}, 0, 0, 0);
    }
#pragma unroll
    for (int r = 0; r < 4; ++r) {
        int rowg = m0 + quad * 4 + r;
        if (rowg < n) {
#pragma unroll
            for (int t = 0; t < 2; ++t)
                out[(size_t)rowg * 32 + t * 16 + l16] = acc2[t][r] + b2f[t * 16 + l16];
        }
    }
}

// ---------------- gather (R11 structure + R13 DPP epilogue, ~41us floor) ----------------
template <bool LN, bool SCALEOUT>
__launch_bounds__(256)
__global__ void gather_s(const unsigned short* __restrict__ xs, const int* __restrict__ offsets,
                         const int* __restrict__ csr_src, const float* __restrict__ dinv,
                         const float* __restrict__ bias, const float* __restrict__ gamma,
                         const float* __restrict__ beta, unsigned short* __restrict__ out, int n) {
    int wave = threadIdx.x >> 6;
    int lane = threadIdx.x & 63;
    int node = blockIdx.x * (blockDim.x >> 6) + wave;
    if (node >= n) return;
    int beg = __builtin_amdgcn_readfirstlane(offsets[node]);
    int end = __builtin_amdgcn_readfirstlane(offsets[node + 1]);
    int deg = end - beg;

    float dd = dinv[node];
    unsigned short selfv = xs[((unsigned)node << 6) + lane];
    float bl = LN ? bias[lane] : 0.f;
    float gl = LN ? gamma[lane] : 1.f;
    float tl = LN ? beta[lane] : 0.f;

    float a0 = 0.f, a1 = 0.f, a2 = 0.f, a3 = 0.f;
    for (int half = 0; half < deg; half += 16) {
        int m = deg - half;
        int sc[16];
#pragma unroll
        for (int j = 0; j < 16; ++j)
            sc[j] = __builtin_amdgcn_readfirstlane(csr_src[beg + half + j]);
        unsigned short v[16];
#pragma unroll
        for (int j = 0; j < 16; ++j) {
            int sel = (j < m) ? sc[j] : sc[0];
            const unsigned short* rp = xs + ((size_t)(unsigned)sel << 6);
            v[j] = rp[lane];
        }
#pragma unroll
        for (int j = 0; j < 16; ++j) {
            float f = bf2f(v[j]);
            if ((j & 3) == 0) a0 += f;
            else if ((j & 3) == 1) a1 += f;
            else if ((j & 3) == 2) a2 += f;
            else a3 += f;
        }
        if (m < 16) a0 -= (float)(16 - m) * bf2f(v[0]);
    }

    float y = (a0 + a1 + a2 + a3 + bf2f(selfv)) * dd;

    if (!LN) {
        out[((unsigned)node << 6) + lane] = f2bf(y);
        return;
    }
    float yb = y + bl;
    float s  = wsum64(yb);
    float sq = wsum64(yb * yb);
    float mu = s * (1.f / 64.f);
    float var = sq * (1.f / 64.f) - mu * mu;
    float rs = rsqrtf(var + LN_EPS);
    float z = (yb - mu) * rs * gl + tl;
    z = z > 0.f ? z : expm1f(z);
    if (SCALEOUT) z *= dd;
    out[((unsigned)node << 6) + lane] = f2bf(z);
}

extern "C" void kernel_launch(void* const* d_in, const int* in_sizes, int n_in,
                              void* d_out, int out_size, void* d_ws, size_t ws_size,
                              hipStream_t stream) {
    const float* x  = (const float*)d_in[0];
    const int* ei   = (const int*)d_in[1];
    const float* W1 = (const float*)d_in[2];
    const float* b1 = (const float*)d_in[3];
    const float* g1 = (const float*)d_in[4];
    const float* be1= (const float*)d_in[5];
    const float* W2 = (const float*)d_in[6];
    const float* b2 = (const float*)d_in[7];
    const float* g2 = (const float*)d_in[8];
    const float* be2= (const float*)d_in[9];
    const float* W3 = (const float*)d_in[10];
    const float* b3 = (const float*)d_in[11];
    const float* g3 = (const float*)d_in[12];
    const float* be3= (const float*)d_in[13];
    const float* lw1= (const float*)d_in[14];
    const float* lb1= (const float*)d_in[15];
    const float* g4 = (const float*)d_in[16];
    const float* be4= (const float*)d_in[17];
    const float* lw2= (const float*)d_in[18];
    const float* lb2= (const float*)d_in[19];
    float* out = (float*)d_out;

    const int E = in_sizes[1] / 2;
    const int* src = ei;
    const int* dst = ei + E;
    const int N = N_NODES;

    // workspace layout (intermediates in bf16)
    unsigned short* bufA = (unsigned short*)d_ws;       // N*128 bf16
    unsigned short* bufB = bufA + (size_t)N * 128;      // N*128 bf16
    float* dinv    = (float*)(bufB + (size_t)N * 128);  // N f32
    int*   offsets = (int*)(dinv + N);                  // N+1
    int*   csr     = offsets + N + 1;                   // E
    int*   tails   = csr + E;                           // NBUCK
    int*   base    = tails + NBUCK;                     // NBUCK+1
    unsigned short* wbase = (unsigned short*)(((size_t)(base + NBUCK + 1) + 15) & ~(size_t)15);
    unsigned short* w1t = wbase;          // [64][128]
    unsigned short* w2t = w1t + 8192;     // [128][64]
    unsigned short* w3t = w2t + 8192;     // [64][128]
    unsigned short* l1t = w3t + 8192;     // [32][64]
    unsigned short* l2t = l1t + 2048;     // [32][32]

    auto cdiv = [](long long a, long long b) { return (int)((a + b - 1) / b); };
    const int NBLK = cdiv(E, EPB);  // 196 for E=1.6M

    const int avg = cdiv(E, NBUCK);
    const int cap = avg + 16 * (int)(sqrtf((float)avg) + 1.f) + 256;
    unsigned* bucket = (unsigned*)bufB;  // slabs alias bufB (~8.4MB), dead after build

    const int GB = cdiv(N, 64);  // mfma gemm grid (64 rows/block)

    // ---- weight prep (once) + CSR build v3 ----
    prep_weights<<<108, 256, 0, stream>>>(W1, W2, W3, lw1, lw2, w1t, w2t, w3t, l1t, l2t);
    hipMemsetAsync(tails, 0, NBUCK * sizeof(int), stream);
    place_reserve<<<NBLK, 512, 0, stream>>>(src, dst, tails, bucket, cap, E);
    scan_base<<<1, 512, 0, stream>>>(tails, base, E);
    build_csr_node<<<NBUCK, 256, 0, stream>>>(bucket, tails, base, offsets, dinv, csr, cap, E);

    // ---- Layer 1: xs0 = dinv*(x @ W1); h1s = dinv*LN_ELU(gather + b1) ----
    mfma_gemm<128, 64, false, false, true, false, true><<<GB, 256, 0, stream>>>(
        x, w1t, nullptr, nullptr, nullptr, bufA, N, dinv);
    gather_s<true, true><<<cdiv(N, 4), 256, 0, stream>>>(bufA, offsets, csr, dinv, b1, g1, be1, bufB, N);

    // ---- Layer 2 (aggregate-first): a2 = gather(h1s) ----
    gather_s<false, false><<<cdiv(N, 4), 256, 0, stream>>>(bufB, offsets, csr, dinv, nullptr, nullptr, nullptr, bufA, N);

    // ---- fused layers 2+3 matmuls: xs2 = dinv * (LN_ELU(a2@W2+b2) @ W3), in-place bufA ----
    gemm23_fused<<<GB, 256, 0, stream>>>(bufA, w2t, b2, g2, be2, w3t, dinv, bufA, N);

    // ---- Layer 3 aggregation: h3 = LN_ELU(gather(xs2) + b3) ----
    gather_s<true, false><<<cdiv(N, 4), 256, 0, stream>>>(bufA, offsets, csr, dinv, b3, g3, be3, bufB, N);

    // ---- fused lin1+lin2: out = LN_ELU(h3 @ lw1 + lb1) @ lw2 + lb2 ----
    lin_fused<<<GB, 256, 0, stream>>>(bufB, l1t, lb1, g4, be4, l2t, lb2, out, N);
}

// Round 15
// 316.778 us; speedup vs baseline: 1.0445x; 1.0445x over previous
//
#include <hip/hip_runtime.h>
#include <math.h>

#define N_NODES 100000
#define LN_EPS 1e-5f
#define NBUCK ((N_NODES + 255) / 256)  // 391 buckets of 256 nodes
#define EPB 8192                        // edges per block in place_reserve

typedef __attribute__((ext_vector_type(8))) short bf16x8;
typedef __attribute__((ext_vector_type(4))) float f32x4;

__device__ __forceinline__ unsigned short f2bf(float f) {
    unsigned int u = __float_as_uint(f);
    return (unsigned short)((u + 0x7FFFu + ((u >> 16) & 1u)) >> 16);
}
__device__ __forceinline__ float bf2f(unsigned short u) {
    return __uint_as_float(((unsigned int)u) << 16);
}

// 64-lane sum via DPP (levels 1-8 on VALU pipe) + xor16 swizzle + shfl32.
__device__ __forceinline__ float wsum64(float x) {
    x += __int_as_float(__builtin_amdgcn_update_dpp(0, __float_as_int(x), 0xB1, 0xF, 0xF, true));
    x += __int_as_float(__builtin_amdgcn_update_dpp(0, __float_as_int(x), 0x4E, 0xF, 0xF, true));
    x += __int_as_float(__builtin_amdgcn_update_dpp(0, __float_as_int(x), 0x141, 0xF, 0xF, true));
    x += __int_as_float(__builtin_amdgcn_update_dpp(0, __float_as_int(x), 0x140, 0xF, 0xF, true));
    x += __int_as_float(__builtin_amdgcn_ds_swizzle(__float_as_int(x), 0x401F));
    x += __shfl_xor(x, 32, 64);
    return x;
}

// ---- weights converted ONCE to transposed bf16 (W^T[out][k]). R13 showed the
// per-block staging pathology was f2bf (5 VALU/elem) + transpose-scatter
// (8-way LDS conflicts) — NOT LDS staging itself. R14 went全global and gemm23
// improved but gemm1/lin regressed (LDS->L2 latency in the MFMA inner loop).
// R15 hybrid: gemm1/lin stage the PREPPED bf16 via cheap vector copy; gemm23
// (51KB LDS would kill occupancy) keeps global weights.
__global__ void prep_weights(const float* __restrict__ W1, const float* __restrict__ W2,
                             const float* __restrict__ W3, const float* __restrict__ L1,
                             const float* __restrict__ L2,
                             unsigned short* __restrict__ w1t, unsigned short* __restrict__ w2t,
                             unsigned short* __restrict__ w3t, unsigned short* __restrict__ l1t,
                             unsigned short* __restrict__ l2t) {
    int i = blockIdx.x * 256 + threadIdx.x;
    if (i < 8192) {                    // W1 [128][64] -> w1t [64][128]
        int k = i >> 6, o = i & 63;
        w1t[o * 128 + k] = f2bf(W1[i]);
    } else if (i < 16384) {            // W2 [64][128] -> w2t [128][64]
        int j = i - 8192, k = j >> 7, o = j & 127;
        w2t[o * 64 + k] = f2bf(W2[j]);
    } else if (i < 24576) {            // W3 [128][64] -> w3t [64][128]
        int j = i - 16384, k = j >> 6, o = j & 63;
        w3t[o * 128 + k] = f2bf(W3[j]);
    } else if (i < 26624) {            // lw1 [64][32] -> l1t [32][64]
        int j = i - 24576, k = j >> 5, o = j & 31;
        l1t[o * 64 + k] = f2bf(L1[j]);
    } else if (i < 27648) {            // lw2 [32][32] -> l2t [32][32]
        int j = i - 26624, k = j >> 5, o = j & 31;
        l2t[o * 32 + k] = f2bf(L2[j]);
    }
}

// ======== CSR build v3 (R13): fixed-cap slab reservation, 3 kernels ========
__global__ void place_reserve(const int* __restrict__ src, const int* __restrict__ dst,
                              int* __restrict__ tails, unsigned* __restrict__ bucket,
                              int cap, int E) {
    __shared__ int hist[NBUCK];
    __shared__ int lcur[NBUCK];
    for (int b = threadIdx.x; b < NBUCK; b += 512) hist[b] = 0;
    __syncthreads();
    int e0 = blockIdx.x * EPB;
#pragma unroll
    for (int i = 0; i < EPB / 512; ++i) {
        int e = e0 + i * 512 + (int)threadIdx.x;
        if (e < E) atomicAdd(&hist[((unsigned)dst[e]) >> 8], 1);
    }
    __syncthreads();
    for (int b = threadIdx.x; b < NBUCK; b += 512) {
        int c = hist[b];
        lcur[b] = (c > 0) ? (b * cap + atomicAdd(&tails[b], c)) : 0;
    }
    __syncthreads();
#pragma unroll
    for (int i = 0; i < EPB / 512; ++i) {
        int e = e0 + i * 512 + (int)threadIdx.x;
        if (e < E) {
            unsigned d = (unsigned)dst[e];
            unsigned s = (unsigned)src[e];
            int p = atomicAdd(&lcur[d >> 8], 1);
            bucket[p] = ((d & 255u) << 24) | s;
        }
    }
}

__global__ void scan_base(const int* __restrict__ tails, int* __restrict__ base, int E) {
    __shared__ int s[512];
    int i = threadIdx.x;
    int v = (i < NBUCK) ? tails[i] : 0;
    s[i] = v;
    __syncthreads();
    for (int off = 1; off < 512; off <<= 1) {
        int t = (i >= off) ? s[i - off] : 0;
        __syncthreads();
        s[i] += t;
        __syncthreads();
    }
    if (i < NBUCK) base[i] = s[i] - v;
    if (i == 0) base[NBUCK] = E;
}

__global__ void build_csr_node(const unsigned* __restrict__ bucket, const int* __restrict__ tails,
                               const int* __restrict__ base, int* __restrict__ offsets,
                               float* __restrict__ dinv, int* __restrict__ csr,
                               int cap, int E) {
    __shared__ int hist[256];
    __shared__ int cur[256];
    int b = blockIdx.x, t = threadIdx.x;
    int r0 = b << 8;
    hist[t] = 0;
    __syncthreads();
    int s0 = b * cap, s1 = s0 + tails[b];
    for (int e = s0 + t; e < s1; e += 256)
        atomicAdd(&hist[bucket[e] >> 24], 1);
    __syncthreads();
    int deg = hist[t];
    for (int off = 1; off < 256; off <<= 1) {
        int tv = (t >= off) ? hist[t - off] : 0;
        __syncthreads();
        hist[t] += tv;
        __syncthreads();
    }
    int excl = hist[t] - deg;
    int node = r0 + t;
    int cbase = base[b];
    if (node < N_NODES) {
        offsets[node] = cbase + excl;
        dinv[node] = rsqrtf((float)deg + 1.f);
        cur[t] = cbase + excl;
    }
    if (node == N_NODES - 1) offsets[N_NODES] = E;
    __syncthreads();
    for (int e = s0 + t; e < s1; e += 256) {
        unsigned u = bucket[e];
        int p = atomicAdd(&cur[u >> 24], 1);
        csr[p] = (int)(u & 0xFFFFFFu);
    }
}

// ---------------- MFMA gemm: Y = X[n,K] @ W; prepped bf16 W^T staged via cheap vector copy ----
template <int K, int OUT, bool LN, bool BIAS, bool AF32, bool OF32, bool SCALED>
__launch_bounds__(256)
__global__ void mfma_gemm(const void* __restrict__ Xv, const unsigned short* __restrict__ WT,
                          const float* __restrict__ bias, const float* __restrict__ gamma,
                          const float* __restrict__ beta, void* __restrict__ Yv, int n,
                          const float* __restrict__ dinvp) {
    constexpr int T  = OUT / 16;
    constexpr int KP = K + 8;
    constexpr int CH = K / 8;  // bf16x8 chunks per row

    __shared__ __align__(16) unsigned short sWT[OUT * KP];
    // cheap staging: already-transposed bf16, 16B vector copy, no conversion,
    // conflict-free writes (consecutive threads -> consecutive 16B chunks)
    for (int i = threadIdx.x; i < OUT * CH; i += 256) {
        int o = i / CH, c = i - o * CH;
        *(bf16x8*)&sWT[o * KP + c * 8] = *(const bf16x8*)(WT + (size_t)o * K + c * 8);
    }
    __syncthreads();

    int wv = threadIdx.x >> 6, lane = threadIdx.x & 63;
    int quad = lane >> 4, l16 = lane & 15;
    int m0 = (blockIdx.x * 4 + wv) * 16;
    int rowc = min(m0 + l16, n - 1);

    f32x4 acc[T];
#pragma unroll
    for (int t = 0; t < T; ++t) acc[t] = (f32x4){0.f, 0.f, 0.f, 0.f};

#pragma unroll
    for (int s = 0; s < K / 32; ++s) {
        int koff = s * 32 + quad * 8;
        bf16x8 af;
        if (AF32) {
            const float4* X4 = (const float4*)Xv;
            size_t base = ((size_t)rowc * K + koff) >> 2;
            float4 a0 = X4[base];
            float4 a1 = X4[base + 1];
            af[0] = (short)f2bf(a0.x); af[1] = (short)f2bf(a0.y);
            af[2] = (short)f2bf(a0.z); af[3] = (short)f2bf(a0.w);
            af[4] = (short)f2bf(a1.x); af[5] = (short)f2bf(a1.y);
            af[6] = (short)f2bf(a1.z); af[7] = (short)f2bf(a1.w);
        } else {
            const unsigned short* Xb = (const unsigned short*)Xv;
            af = *(const bf16x8*)(Xb + (size_t)rowc * K + koff);
        }
#pragma unroll
        for (int t = 0; t < T; ++t) {
            const bf16x8 bfrag = *(const bf16x8*)&sWT[(t * 16 + l16) * KP + koff];
            acc[t] = __builtin_amdgcn_mfma_f32_16x16x32_bf16(af, bfrag, acc[t], 0, 0, 0);
        }
    }

    float bj[T], gj[T], btj[T];
#pragma unroll
    for (int t = 0; t < T; ++t) {
        int c = t * 16 + l16;
        bj[t]  = BIAS ? bias[c] : 0.f;
        gj[t]  = LN ? gamma[c] : 1.f;
        btj[t] = LN ? beta[c] : 0.f;
    }

    float* Yf = (float*)Yv;
    unsigned short* Yb = (unsigned short*)Yv;

    if (LN) {
        float s[4] = {0.f, 0.f, 0.f, 0.f}, sq[4] = {0.f, 0.f, 0.f, 0.f};
#pragma unroll
        for (int t = 0; t < T; ++t)
#pragma unroll
            for (int r = 0; r < 4; ++r) {
                float v = acc[t][r] + bj[t];
                s[r] += v;
                sq[r] += v * v;
            }
#pragma unroll
        for (int off = 1; off < 16; off <<= 1)
#pragma unroll
            for (int r = 0; r < 4; ++r) {
                s[r] += __shfl_xor(s[r], off, 64);
                sq[r] += __shfl_xor(sq[r], off, 64);
            }
        float mu[4], rs[4];
#pragma unroll
        for (int r = 0; r < 4; ++r) {
            mu[r] = s[r] / OUT;
            float var = sq[r] / OUT - mu[r] * mu[r];
            rs[r] = rsqrtf(var + LN_EPS);
        }
#pragma unroll
        for (int r = 0; r < 4; ++r) {
            int rowg = m0 + quad * 4 + r;
            if (rowg < n) {
                float dv = SCALED ? dinvp[rowg] : 1.f;
#pragma unroll
                for (int t = 0; t < T; ++t) {
                    float y = (acc[t][r] + bj[t] - mu[r]) * rs[r] * gj[t] + btj[t];
                    y = y > 0.f ? y : expm1f(y);
                    if (SCALED) y *= dv;
                    size_t idx = (size_t)rowg * OUT + t * 16 + l16;
                    if (OF32) Yf[idx] = y; else Yb[idx] = f2bf(y);
                }
            }
        }
    } else {
#pragma unroll
        for (int r = 0; r < 4; ++r) {
            int rowg = m0 + quad * 4 + r;
            if (rowg < n) {
                float dv = SCALED ? dinvp[rowg] : 1.f;
#pragma unroll
                for (int t = 0; t < T; ++t) {
                    float y = acc[t][r] + bj[t];
                    if (SCALED) y *= dv;
                    size_t idx = (size_t)rowg * OUT + t * 16 + l16;
                    if (OF32) Yf[idx] = y; else Yb[idx] = f2bf(y);
                }
            }
        }
    }
}

// ---------------- fused gemm2+gemm3: xs2 = dinv * (LN_ELU(a2@W2+b2) @ W3) ----------------
// R14 form (global weights): LDS would be 51KB -> occupancy cliff. Verified
// improvement in R14 (54us -> <41). In-place X==Y safe (wave reads own rows).
__launch_bounds__(256)
__global__ void gemm23_fused(const unsigned short* __restrict__ X,
                             const unsigned short* __restrict__ w2t, const float* __restrict__ b2f,
                             const float* __restrict__ g2, const float* __restrict__ be2,
                             const unsigned short* __restrict__ w3t, const float* __restrict__ dinvp,
                             unsigned short* __restrict__ Y, int n) {
    constexpr int TS = 136;
    __shared__ __align__(16) unsigned short sT[4][16 * TS];   // 17.4KB

    int wv = threadIdx.x >> 6, lane = threadIdx.x & 63;
    int quad = lane >> 4, l16 = lane & 15;
    int m0 = (blockIdx.x * 4 + wv) * 16;
    int rowc = min(m0 + l16, n - 1);

    // MFMA1: [16x64] @ W2 -> [16x128]
    f32x4 acc[8];
#pragma unroll
    for (int t = 0; t < 8; ++t) acc[t] = (f32x4){0.f, 0.f, 0.f, 0.f};
#pragma unroll
    for (int s = 0; s < 2; ++s) {
        int koff = s * 32 + quad * 8;
        bf16x8 af = *(const bf16x8*)(X + (size_t)rowc * 64 + koff);
#pragma unroll
        for (int t = 0; t < 8; ++t) {
            const bf16x8 bfrag = *(const bf16x8*)(w2t + (size_t)(t * 16 + l16) * 64 + koff);
            acc[t] = __builtin_amdgcn_mfma_f32_16x16x32_bf16(af, bfrag, acc[t], 0, 0, 0);
        }
    }

    // bias + LN(128) + ELU -> transpose tile
    float bj[8], gj[8], btj[8];
#pragma unroll
    for (int t = 0; t < 8; ++t) {
        int c = t * 16 + l16;
        bj[t] = b2f[c]; gj[t] = g2[c]; btj[t] = be2[c];
    }
    float s4[4] = {0.f, 0.f, 0.f, 0.f}, sq4[4] = {0.f, 0.f, 0.f, 0.f};
#pragma unroll
    for (int t = 0; t < 8; ++t)
#pragma unroll
        for (int r = 0; r < 4; ++r) {
            float v = acc[t][r] + bj[t];
            s4[r] += v;
            sq4[r] += v * v;
        }
#pragma unroll
    for (int off = 1; off < 16; off <<= 1)
#pragma unroll
        for (int r = 0; r < 4; ++r) {
            s4[r] += __shfl_xor(s4[r], off, 64);
            sq4[r] += __shfl_xor(sq4[r], off, 64);
        }
#pragma unroll
    for (int r = 0; r < 4; ++r) {
        float mu = s4[r] * (1.f / 128.f);
        float var = sq4[r] * (1.f / 128.f) - mu * mu;
        float rs = rsqrtf(var + LN_EPS);
#pragma unroll
        for (int t = 0; t < 8; ++t) {
            float z = (acc[t][r] + bj[t] - mu) * rs * gj[t] + btj[t];
            z = z > 0.f ? z : expm1f(z);
            sT[wv][(quad * 4 + r) * TS + t * 16 + l16] = f2bf(z);
        }
    }
    __syncthreads();

    // MFMA2: [16x128] @ W3 -> [16x64], scale by dinv
    f32x4 acc2[4];
#pragma unroll
    for (int t = 0; t < 4; ++t) acc2[t] = (f32x4){0.f, 0.f, 0.f, 0.f};
#pragma unroll
    for (int s = 0; s < 4; ++s) {
        int koff = s * 32 + quad * 8;
        bf16x8 af = *(const bf16x8*)&sT[wv][l16 * TS + koff];
#pragma unroll
        for (int t = 0; t < 4; ++t) {
            const bf16x8 bfrag = *(const bf16x8*)(w3t + (size_t)(t * 16 + l16) * 128 + koff);
            acc2[t] = __builtin_amdgcn_mfma_f32_16x16x32_bf16(af, bfrag, acc2[t], 0, 0, 0);
        }
    }
#pragma unroll
    for (int r = 0; r < 4; ++r) {
        int rowg = m0 + quad * 4 + r;
        if (rowg < n) {
            float dv = dinvp[rowg];
#pragma unroll
            for (int t = 0; t < 4; ++t)
                Y[(size_t)rowg * 64 + t * 16 + l16] = f2bf(acc2[t][r] * dv);
        }
    }
}

// ---------------- fused lin1+lin2: prepped bf16 weights staged via cheap copy ----------------
__launch_bounds__(256)
__global__ void lin_fused(const unsigned short* __restrict__ X, const unsigned short* __restrict__ l1t,
                          const float* __restrict__ b1f, const float* __restrict__ g,
                          const float* __restrict__ be, const unsigned short* __restrict__ l2t,
                          const float* __restrict__ b2f, float* __restrict__ out, int n) {
    constexpr int KP1 = 72;
    constexpr int KP2 = 40;
    constexpr int TS  = 56;
    __shared__ __align__(16) unsigned short sW1[32 * KP1];  // 4.5KB
    __shared__ __align__(16) unsigned short sW2[32 * KP2];  // 2.5KB
    __shared__ __align__(16) unsigned short sT[4][16 * TS];

    for (int i = threadIdx.x; i < 32 * 8; i += 256) {       // l1t: 32 rows x 8 chunks
        int o = i >> 3, c = i & 7;
        *(bf16x8*)&sW1[o * KP1 + c * 8] = *(const bf16x8*)(l1t + (size_t)o * 64 + c * 8);
    }
    for (int i = threadIdx.x; i < 32 * 4; i += 256) {       // l2t: 32 rows x 4 chunks
        int o = i >> 2, c = i & 3;
        *(bf16x8*)&sW2[o * KP2 + c * 8] = *(const bf16x8*)(l2t + (size_t)o * 32 + c * 8);
    }
    __syncthreads();

    int wv = threadIdx.x >> 6, lane = threadIdx.x & 63;
    int quad = lane >> 4, l16 = lane & 15;
    int m0 = (blockIdx.x * 4 + wv) * 16;
    int rowc = min(m0 + l16, n - 1);

    f32x4 acc[2];
    acc[0] = (f32x4){0.f, 0.f, 0.f, 0.f};
    acc[1] = (f32x4){0.f, 0.f, 0.f, 0.f};
#pragma unroll
    for (int s = 0; s < 2; ++s) {
        int koff = s * 32 + quad * 8;
        bf16x8 af = *(const bf16x8*)(X + (size_t)rowc * 64 + koff);
#pragma unroll
        for (int t = 0; t < 2; ++t) {
            const bf16x8 bfrag = *(const bf16x8*)&sW1[(t * 16 + l16) * KP1 + koff];
            acc[t] = __builtin_amdgcn_mfma_f32_16x16x32_bf16(af, bfrag, acc[t], 0, 0, 0);
        }
    }

    float bj[2], gj[2], btj[2];
#pragma unroll
    for (int t = 0; t < 2; ++t) {
        int c = t * 16 + l16;
        bj[t] = b1f[c]; gj[t] = g[c]; btj[t] = be[c];
    }
    float s4[4] = {0.f, 0.f, 0.f, 0.f}, sq4[4] = {0.f, 0.f, 0.f, 0.f};
#pragma unroll
    for (int t = 0; t < 2; ++t)
#pragma unroll
        for (int r = 0; r < 4; ++r) {
            float v = acc[t][r] + bj[t];
            s4[r] += v;
            sq4[r] += v * v;
        }
#pragma unroll
    for (int off = 1; off < 16; off <<= 1)
#pragma unroll
        for (int r = 0; r < 4; ++r) {
            s4[r] += __shfl_xor(s4[r], off, 64);
            sq4[r] += __shfl_xor(sq4[r], off, 64);
        }
#pragma unroll
    for (int r = 0; r < 4; ++r) {
        float mu = s4[r] * (1.f / 32.f);
        float var = sq4[r] * (1.f / 32.f) - mu * mu;
        float rs = rsqrtf(var + LN_EPS);
#pragma unroll
        for (int t = 0; t < 2; ++t) {
            float z = (acc[t][r] + bj[t] - mu) * rs * gj[t] + btj[t];
            z = z > 0.f ? z : expm1f(z);
            sT[wv][(quad * 4 + r) * TS + t * 16 + l16] = f2bf(z);
        }
    }
    __syncthreads();

    bf16x8 a2 = *(const bf16x8*)&sT[wv][l16 * TS + quad * 8];
    f32x4 acc2[2];
#pragma unroll
    for (int t = 0; t < 2; ++t) {
        const bf16x8 bfrag = *(const bf16x8*)&sW2[(t * 16 + l16) * KP2 + quad * 8];
        acc2[t] = __builtin_amdgcn_mfma_f32_16x16x32_bf16(
            a2, bfrag, (f32x4){0.f, 0.f, 0.f, 0.f}, 0, 0, 0);
    }
#pragma unroll
    for (int r = 0; r < 4; ++r) {
        int rowg = m0 + quad * 4 + r;
        if (rowg < n) {
#pragma unroll
            for (int t = 0; t < 2; ++t)
                out[(size_t)rowg * 32 + t * 16 + l16] = acc2[t][r] + b2f[t * 16 + l16];
        }
    }
}

// ---------------- gather (R11 structure + R13 DPP epilogue, ~41us floor) ----------------
template <bool LN, bool SCALEOUT>
__launch_bounds__(256)
__global__ void gather_s(const unsigned short* __restrict__ xs, const int* __restrict__ offsets,
                         const int* __restrict__ csr_src, const float* __restrict__ dinv,
                         const float* __restrict__ bias, const float* __restrict__ gamma,
                         const float* __restrict__ beta, unsigned short* __restrict__ out, int n) {
    int wave = threadIdx.x >> 6;
    int lane = threadIdx.x & 63;
    int node = blockIdx.x * (blockDim.x >> 6) + wave;
    if (node >= n) return;
    int beg = __builtin_amdgcn_readfirstlane(offsets[node]);
    int end = __builtin_amdgcn_readfirstlane(offsets[node + 1]);
    int deg = end - beg;

    float dd = dinv[node];
    unsigned short selfv = xs[((unsigned)node << 6) + lane];
    float bl = LN ? bias[lane] : 0.f;
    float gl = LN ? gamma[lane] : 1.f;
    float tl = LN ? beta[lane] : 0.f;

    float a0 = 0.f, a1 = 0.f, a2 = 0.f, a3 = 0.f;
    for (int half = 0; half < deg; half += 16) {
        int m = deg - half;
        int sc[16];
#pragma unroll
        for (int j = 0; j < 16; ++j)
            sc[j] = __builtin_amdgcn_readfirstlane(csr_src[beg + half + j]);
        unsigned short v[16];
#pragma unroll
        for (int j = 0; j < 16; ++j) {
            int sel = (j < m) ? sc[j] : sc[0];
            const unsigned short* rp = xs + ((size_t)(unsigned)sel << 6);
            v[j] = rp[lane];
        }
#pragma unroll
        for (int j = 0; j < 16; ++j) {
            float f = bf2f(v[j]);
            if ((j & 3) == 0) a0 += f;
            else if ((j & 3) == 1) a1 += f;
            else if ((j & 3) == 2) a2 += f;
            else a3 += f;
        }
        if (m < 16) a0 -= (float)(16 - m) * bf2f(v[0]);
    }

    float y = (a0 + a1 + a2 + a3 + bf2f(selfv)) * dd;

    if (!LN) {
        out[((unsigned)node << 6) + lane] = f2bf(y);
        return;
    }
    float yb = y + bl;
    float s  = wsum64(yb);
    float sq = wsum64(yb * yb);
    float mu = s * (1.f / 64.f);
    float var = sq * (1.f / 64.f) - mu * mu;
    float rs = rsqrtf(var + LN_EPS);
    float z = (yb - mu) * rs * gl + tl;
    z = z > 0.f ? z : expm1f(z);
    if (SCALEOUT) z *= dd;
    out[((unsigned)node << 6) + lane] = f2bf(z);
}

extern "C" void kernel_launch(void* const* d_in, const int* in_sizes, int n_in,
                              void* d_out, int out_size, void* d_ws, size_t ws_size,
                              hipStream_t stream) {
    const float* x  = (const float*)d_in[0];
    const int* ei   = (const int*)d_in[1];
    const float* W1 = (const float*)d_in[2];
    const float* b1 = (const float*)d_in[3];
    const float* g1 = (const float*)d_in[4];
    const float* be1= (const float*)d_in[5];
    const float* W2 = (const float*)d_in[6];
    const float* b2 = (const float*)d_in[7];
    const float* g2 = (const float*)d_in[8];
    const float* be2= (const float*)d_in[9];
    const float* W3 = (const float*)d_in[10];
    const float* b3 = (const float*)d_in[11];
    const float* g3 = (const float*)d_in[12];
    const float* be3= (const float*)d_in[13];
    const float* lw1= (const float*)d_in[14];
    const float* lb1= (const float*)d_in[15];
    const float* g4 = (const float*)d_in[16];
    const float* be4= (const float*)d_in[17];
    const float* lw2= (const float*)d_in[18];
    const float* lb2= (const float*)d_in[19];
    float* out = (float*)d_out;

    const int E = in_sizes[1] / 2;
    const int* src = ei;
    const int* dst = ei + E;
    const int N = N_NODES;

    // workspace layout (intermediates in bf16)
    unsigned short* bufA = (unsigned short*)d_ws;       // N*128 bf16
    unsigned short* bufB = bufA + (size_t)N * 128;      // N*128 bf16
    float* dinv    = (float*)(bufB + (size_t)N * 128);  // N f32
    int*   offsets = (int*)(dinv + N);                  // N+1
    int*   csr     = offsets + N + 1;                   // E
    int*   tails   = csr + E;                           // NBUCK
    int*   base    = tails + NBUCK;                     // NBUCK+1
    unsigned short* wbase = (unsigned short*)(((size_t)(base + NBUCK + 1) + 15) & ~(size_t)15);
    unsigned short* w1t = wbase;          // [64][128]
    unsigned short* w2t = w1t + 8192;     // [128][64]
    unsigned short* w3t = w2t + 8192;     // [64][128]
    unsigned short* l1t = w3t + 8192;     // [32][64]
    unsigned short* l2t = l1t + 2048;     // [32][32]

    auto cdiv = [](long long a, long long b) { return (int)((a + b - 1) / b); };
    const int NBLK = cdiv(E, EPB);  // 196 for E=1.6M

    const int avg = cdiv(E, NBUCK);
    const int cap = avg + 16 * (int)(sqrtf((float)avg) + 1.f) + 256;
    unsigned* bucket = (unsigned*)bufB;  // slabs alias bufB (~8.4MB), dead after build

    const int GB = cdiv(N, 64);  // mfma gemm grid (64 rows/block)

    // ---- weight prep (once) + CSR build v3 ----
    prep_weights<<<108, 256, 0, stream>>>(W1, W2, W3, lw1, lw2, w1t, w2t, w3t, l1t, l2t);
    hipMemsetAsync(tails, 0, NBUCK * sizeof(int), stream);
    place_reserve<<<NBLK, 512, 0, stream>>>(src, dst, tails, bucket, cap, E);
    scan_base<<<1, 512, 0, stream>>>(tails, base, E);
    build_csr_node<<<NBUCK, 256, 0, stream>>>(bucket, tails, base, offsets, dinv, csr, cap, E);

    // ---- Layer 1: xs0 = dinv*(x @ W1); h1s = dinv*LN_ELU(gather + b1) ----
    mfma_gemm<128, 64, false, false, true, false, true><<<GB, 256, 0, stream>>>(
        x, w1t, nullptr, nullptr, nullptr, bufA, N, dinv);
    gather_s<true, true><<<cdiv(N, 4), 256, 0, stream>>>(bufA, offsets, csr, dinv, b1, g1, be1, bufB, N);

    // ---- Layer 2 (aggregate-first): a2 = gather(h1s) ----
    gather_s<false, false><<<cdiv(N, 4), 256, 0, stream>>>(bufB, offsets, csr, dinv, nullptr, nullptr, nullptr, bufA, N);

    // ---- fused layers 2+3 matmuls: xs2 = dinv * (LN_ELU(a2@W2+b2) @ W3), in-place bufA ----
    gemm23_fused<<<GB, 256, 0, stream>>>(bufA, w2t, b2, g2, be2, w3t, dinv, bufA, N);

    // ---- Layer 3 aggregation: h3 = LN_ELU(gather(xs2) + b3) ----
    gather_s<true, false><<<cdiv(N, 4), 256, 0, stream>>>(bufA, offsets, csr, dinv, b3, g3, be3, bufB, N);

    // ---- fused lin1+lin2: out = LN_ELU(h3 @ lw1 + lb1) @ lw2 + lb2 ----
    lin_fused<<<GB, 256, 0, stream>>>(bufB, l1t, lb1, g4, be4, l2t, lb2, out, N);
}